// Round 13
// baseline (222.497 us; speedup 1.0000x reference)
//
#include <hip/hip_runtime.h>

#define BATCH    4096
#define SENS     64
#define UNITS    128
#define MOTOR_N  32
#define UNFOLDS  6
#define NB       4
#define ROWS_PER_BLOCK 16
#define NBLOCKS  (BATCH / ROWS_PER_BLOCK)   // 256
#define NGROUPS  (ROWS_PER_BLOCK / NB)      // 4
#define VP 140   // padded v row: f(j)=j+(j>>5)*4, max f(127)=139; 560B row, 16B-aligned
#define XP 68    // padded x row: max f(63)=67; 272B row, 16B-aligned

#define LOG2E 1.4426950408889634f

__device__ __forceinline__ float fast_exp2(float x) { return __builtin_amdgcn_exp2f(x); }
__device__ __forceinline__ float fast_rcp(float x)  { return __builtin_amdgcn_rcpf(x); }
__device__ __forceinline__ unsigned f2bf(float x) {          // f32 -> bf16 bits (RNE)
    unsigned v = __float_as_uint(x);
    v += 0x7fffu + ((v >> 16) & 1u);
    return v >> 16;
}
__device__ __forceinline__ float bf_lo(unsigned p) { return __uint_as_float(p << 16); }
__device__ __forceinline__ float bf_hi(unsigned p) { return __uint_as_float(p & 0xffff0000u); }
__device__ __forceinline__ int vpad(int j) { return j + ((j >> 5) << 2); }

// ---------------------------------------------------------------------------
// Fused LTC. 1024 thr: u = t>>3 (unit), c = t&7 (chunk) -> a unit's 8 chunks
// share a wave: chunk-reduction = __shfl_xor(,1/2/4,8). No pn/pd LDS, one
// barrier per ODE step (double-buffered v_lds).
// ROUND-12 LESSON: allocator pins VGPR budget at ~64 regardless of
// waves_per_eu; fit it by design: rgl/rgb f32 (exp2 path, exact) = 32 regs,
// ws packed bf16 pairs = 8 regs. Sensory params are phase-transient (sensory
// -> nb/db_lds precomputed before recurrent params load). <=64 VGPR also
// gives 2 blocks/CU (100% occupancy vs 45%).
// LDS padded (f(j)=j+(j>>5)*4) so each chunk's float4 v-reads are
// bank-conflict-free across the 8 c-lanes.
// ---------------------------------------------------------------------------
__global__ __launch_bounds__(1024)
void ltc_fused(
    const float* __restrict__ inputs,  const float* __restrict__ state,
    const float* __restrict__ gleak,   const float* __restrict__ vleak,
    const float* __restrict__ cm,
    const float* __restrict__ sigma,   const float* __restrict__ mu,
    const float* __restrict__ w,       const float* __restrict__ erev,
    const float* __restrict__ s_sigma, const float* __restrict__ s_mu,
    const float* __restrict__ s_w,     const float* __restrict__ s_erev,
    const float* __restrict__ input_w, const float* __restrict__ input_b,
    const float* __restrict__ output_w,const float* __restrict__ output_b,
    const int*   __restrict__ mask,    const int* __restrict__ s_mask,
    float* __restrict__ out, float* __restrict__ next_state)
{
    __shared__ __align__(16) float x_lds[ROWS_PER_BLOCK][XP];
    __shared__ float nb_lds[ROWS_PER_BLOCK][UNITS];
    __shared__ float db_lds[ROWS_PER_BLOCK][UNITS];
    __shared__ __align__(16) float v_lds[2][NB][VP];

    const int t = threadIdx.x;
    const int u = t >> 3;            // 0..127
    const int c = t & 7;             // 0..7
    const int vread = c * 16 + ((c >> 1) << 2);   // f(c*16)
    const int xread = c * 8  + ((c >> 2) << 2);   // f(c*8)

    const float cmt = cm[u] * 6.0f;
    const float glv = gleak[u];
    const float nb0 = glv * vleak[u];
    const float db0 = cmt + glv + 1e-8f;

    {   // stage x: 1024 threads -> 16 rows x 64 (padded layout)
        const int r = t >> 6, s = t & 63;
        x_lds[r][vpad(s) == s + ((s >> 5) << 2) ? s + ((s >> 5) << 2) : 0] =
            0.0f;  // (dummy to keep expression simple below)
        x_lds[r][s + ((s >> 5) << 2)] =
            inputs[(blockIdx.x * ROWS_PER_BLOCK + r) * SENS + s] * input_w[s] + input_b[s];
    }

    // ---- sensory params (transient): 8 syn/thread, presyn rows c*8..c*8+7
    float sgl[8], sgb[8];
    unsigned swsp[4];
#pragma unroll
    for (int k2 = 0; k2 < 4; ++k2) {
        float wt[2];
#pragma unroll
        for (int e = 0; e < 2; ++e) {
            int k = k2 * 2 + e;
            int idx = (c * 8 + k) * UNITS + u;
            float sg = s_sigma[idx] * LOG2E;
            float wv = s_w[idx] * (s_mask[idx] != 0 ? 1.0f : 0.0f);
            sgl[k] = -sg;
            sgb[k] = sg * s_mu[idx];
            wt[e]  = wv * s_erev[idx];
        }
        swsp[k2] = (f2bf(wt[1]) << 16) | f2bf(wt[0]);
    }
    __syncthreads();                 // x_lds ready

    // ---- sensory phase: nb/db_lds[row][u] for all 16 rows ----
#pragma unroll 1
    for (int row = 0; row < ROWS_PER_BLOCK; ++row) {
        const float4* xp = (const float4*)&x_lds[row][xread];
        float4 xa = xp[0], xb = xp[1];
        float xs[8] = {xa.x, xa.y, xa.z, xa.w, xb.x, xb.y, xb.z, xb.w};
        float nsum = 0.f, dsum = 0.f;
#pragma unroll
        for (int k = 0; k < 8; ++k) {
            float e  = fast_exp2(fmaf(sgl[k], xs[k], sgb[k]));
            float r  = fast_rcp(1.0f + e);
            float ws = (k & 1) ? bf_hi(swsp[k >> 1]) : bf_lo(swsp[k >> 1]);
            nsum = fmaf(ws, r, nsum);
            dsum = fmaf(fabsf(ws), r, dsum);
        }
        nsum += __shfl_xor(nsum, 1, 8);
        nsum += __shfl_xor(nsum, 2, 8);
        nsum += __shfl_xor(nsum, 4, 8);
        dsum += __shfl_xor(dsum, 1, 8);
        dsum += __shfl_xor(dsum, 2, 8);
        dsum += __shfl_xor(dsum, 4, 8);
        if (c == 0) {
            nb_lds[row][u] = nb0 + nsum;
            db_lds[row][u] = db0 + dsum;
        }
    }

    // ---- recurrent params: 16 syn/thread, presyn rows c*16..c*16+15 ----
    float rgl[16], rgb[16];
    unsigned rwsp[8];
#pragma unroll
    for (int k2 = 0; k2 < 8; ++k2) {
        float wt[2];
#pragma unroll
        for (int e = 0; e < 2; ++e) {
            int k = k2 * 2 + e;
            int idx = (c * 16 + k) * UNITS + u;
            float sg = sigma[idx] * LOG2E;
            float wv = w[idx] * (mask[idx] != 0 ? 1.0f : 0.0f);
            rgl[k] = -sg;
            rgb[k] = sg * mu[idx];
            wt[e]  = wv * erev[idx];
        }
        rwsp[k2] = (f2bf(wt[1]) << 16) | f2bf(wt[0]);
    }
#pragma unroll
    for (int k = 0; k < 16; ++k)
        asm volatile("" : "+v"(rgl[k]), "+v"(rgb[k]));
#pragma unroll
    for (int k2 = 0; k2 < 8; ++k2)
        asm volatile("" : "+v"(rwsp[k2]));

    __syncthreads();                 // nb/db ready

    // ---- 4 groups x 6 ODE unfolds ----
#pragma unroll 1
    for (int g = 0; g < NGROUPS; ++g) {
        const int b0 = blockIdx.x * ROWS_PER_BLOCK + g * NB;
        if (t < NB * UNITS) {        // v init (padded)
            int b = t >> 7, j = t & 127;
            v_lds[0][b][vpad(j)] = state[(b0 + b) * UNITS + j];
        }
        __syncthreads();

        float vc[NB];
#pragma unroll
        for (int b = 0; b < NB; ++b) vc[b] = v_lds[0][b][vpad(u)];

        int p = 0;
#pragma unroll 1
        for (int step = 0; step < UNFOLDS; ++step) {
#pragma unroll
            for (int b = 0; b < NB; ++b) {
                const float4* vp4 = (const float4*)&v_lds[p][b][vread];
                float nsum = 0.f, dsum = 0.f;
#pragma unroll
                for (int q = 0; q < 4; ++q) {
                    float4 v4 = vp4[q];
                    const float* vf = (const float*)&v4;
#pragma unroll
                    for (int jj = 0; jj < 4; ++jj) {
                        int k = q * 4 + jj;
                        float e  = fast_exp2(fmaf(rgl[k], vf[jj], rgb[k]));
                        float r  = fast_rcp(1.0f + e);
                        float ws = (k & 1) ? bf_hi(rwsp[k >> 1]) : bf_lo(rwsp[k >> 1]);
                        nsum = fmaf(ws, r, nsum);
                        dsum = fmaf(fabsf(ws), r, dsum);
                    }
                }
                nsum += __shfl_xor(nsum, 1, 8);
                nsum += __shfl_xor(nsum, 2, 8);
                nsum += __shfl_xor(nsum, 4, 8);
                dsum += __shfl_xor(dsum, 1, 8);
                dsum += __shfl_xor(dsum, 2, 8);
                dsum += __shfl_xor(dsum, 4, 8);
                const int row = g * NB + b;
                float vnew = fmaf(cmt, vc[b], nsum + nb_lds[row][u])
                           * fast_rcp(dsum + db_lds[row][u]);
                vc[b] = vnew;
                if (c == 0) v_lds[p ^ 1][b][vpad(u)] = vnew;
            }
            __syncthreads();         // vnew visible; also fences next reuse
            p ^= 1;
        }

        if (c == 0) {
#pragma unroll
            for (int b = 0; b < NB; ++b) {
                const int row = b0 + b;
                next_state[row * UNITS + u] = vc[b];
                if (u < MOTOR_N)
                    out[row * MOTOR_N + u] = vc[b] * output_w[u] + output_b[u];
            }
        }
        // no trailing barrier: last step's __syncthreads separates all v_lds uses
    }
}

// ---------------------------------------------------------------------------
extern "C" void kernel_launch(void* const* d_in, const int* in_sizes, int n_in,
                              void* d_out, int out_size, void* d_ws, size_t ws_size,
                              hipStream_t stream) {
    const float* inputs   = (const float*)d_in[0];
    const float* state    = (const float*)d_in[1];
    const float* gleak    = (const float*)d_in[2];
    const float* vleak    = (const float*)d_in[3];
    const float* cm       = (const float*)d_in[4];
    const float* sigma    = (const float*)d_in[5];
    const float* mu       = (const float*)d_in[6];
    const float* w        = (const float*)d_in[7];
    const float* erev     = (const float*)d_in[8];
    const float* s_sigma  = (const float*)d_in[9];
    const float* s_mu     = (const float*)d_in[10];
    const float* s_w      = (const float*)d_in[11];
    const float* s_erev   = (const float*)d_in[12];
    const float* input_w  = (const float*)d_in[13];
    const float* input_b  = (const float*)d_in[14];
    const float* output_w = (const float*)d_in[15];
    const float* output_b = (const float*)d_in[16];
    const int*   mask     = (const int*)d_in[17];
    const int*   s_mask   = (const int*)d_in[18];

    float* out        = (float*)d_out;                   // [B, 32]
    float* next_state = out + (size_t)BATCH * MOTOR_N;   // [B, 128]

    ltc_fused<<<NBLOCKS, 1024, 0, stream>>>(
        inputs, state, gleak, vleak, cm, sigma, mu, w, erev,
        s_sigma, s_mu, s_w, s_erev, input_w, input_b, output_w, output_b,
        mask, s_mask, out, next_state);
}